// Round 2
// baseline (576.110 us; speedup 1.0000x reference)
//
#include <hip/hip_runtime.h>

typedef unsigned short u16;
typedef __attribute__((ext_vector_type(8))) __bf16 bf16x8;
typedef __attribute__((ext_vector_type(4))) float floatx4;

#define DEV static __device__ __forceinline__

DEV float lo2f(unsigned v){ return __uint_as_float(v << 16); }
DEV float hi2f(unsigned v){ return __uint_as_float(v & 0xffff0000u); }
DEV float bu2f(u16 v){ return __uint_as_float(((unsigned)v) << 16); }
DEV u16 f2b(float f){
  unsigned u = __float_as_uint(f);
  return (u16)((u + 0x7fffu + ((u >> 16) & 1u)) >> 16);
}
DEV float geluf(float x){ return 0.5f * x * (1.0f + erff(x * 0.70710678118654752440f)); }

// ---------------------------------------------------------------------------
// Weight pre-pack: f32 B (K x N row-major) -> bf16 frag layout
//   dst[((kk*N + n)*4 + q)*8 + j] = B[kk*32 + q*8 + j][n]
// so a lane's b-frag (8 bf16, 16B) is one contiguous dwordx4 load.
// ---------------------------------------------------------------------------
__global__ __launch_bounds__(256) void k_pack(
    const float* __restrict__ lw1, const float* __restrict__ lw2, const float* __restrict__ poolw,
    const float* __restrict__ mw1, const float* __restrict__ mw2, const float* __restrict__ uw1,
    const float* __restrict__ uw2, const float* __restrict__ bcw, const float* __restrict__ headw,
    u16* __restrict__ dst)
{
  int b = blockIdx.x;
  const float* src; int N, off, remap = 0;
  if      (b < 128){            src = lw1;  N=256; off = 0;      }
  else if (b < 256){ b -= 128;  src = lw2;  N=128; off = 32768;  }
  else if (b < 320){ b -= 256;  src = poolw;N=128; off = 65536;  }
  else if (b < 448){ b -= 320;  src = mw1;  N=256; off = 81920;  remap = 1; }
  else if (b < 512){ b -= 448;  src = mw2;  N=128; off = 114688; }
  else if (b < 640){ b -= 512;  src = uw1;  N=128; off = 131072; }
  else if (b < 704){ b -= 640;  src = uw2;  N=128; off = 163840; }
  else if (b < 768){ b -= 704;  src = bcw;  N=128; off = 180224; }
  else             { b -= 768;  src = headw;N=256; off = 196608; }
  int e = b * 256 + threadIdx.x;
  int j = e & 7, q = (e >> 3) & 3, rest = e >> 5;
  int n = rest % N, kk = rest / N;
  int k = kk * 32 + q * 8 + j;
  float v;
  if (remap) v = (n < 128) ? src[k * 128 + n] : src[(128 + k) * 128 + (n - 128)];
  else       v = src[k * N + n];
  dst[off + e] = f2b(v);
}

// ---------------------------------------------------------------------------
// k_local: h = emb[tok]+pos[c]; local = h + gelu(LN(h)@lw1+lb1)@lw2+lb2
// 64 tokens per block, 4 waves; fused LN + two MFMA GEMMs. Output bf16.
// ---------------------------------------------------------------------------
__global__ __launch_bounds__(256) void k_local(
    const int* __restrict__ x, const float* __restrict__ emb, const float* __restrict__ pos,
    const u16* __restrict__ lw1p, const float* __restrict__ lb1,
    const u16* __restrict__ lw2p, const float* __restrict__ lb2,
    const float* __restrict__ g, const float* __restrict__ bb, u16* __restrict__ outL)
{
  __shared__ u16 sA[64][136];     // LN'd activations bf16
  __shared__ u16 sY[64][264];     // gelu hidden bf16
  __shared__ int stok[64];
  __shared__ float ps[64][4], ps2[64][4], smu[64], srs[64];
  const int tid = threadIdx.x;
  const int m0 = blockIdx.x * 64;
  if (tid < 64) stok[tid] = x[m0 + tid];
  __syncthreads();
  const int r = tid >> 2, sg = tid & 3;
  float h[32];
  {
    const int tok = stok[r];
    const int c = (m0 + r) & 7;
    const float4* e4 = (const float4*)(emb + (size_t)tok * 128 + sg * 32);
    const float4* p4 = (const float4*)(pos + c * 128 + sg * 32);
    float s = 0.f, s2 = 0.f;
#pragma unroll
    for (int i = 0; i < 8; i++){
      float4 ev = e4[i], pv = p4[i];
      float v0 = ev.x + pv.x, v1 = ev.y + pv.y, v2 = ev.z + pv.z, v3 = ev.w + pv.w;
      h[i * 4 + 0] = v0; h[i * 4 + 1] = v1; h[i * 4 + 2] = v2; h[i * 4 + 3] = v3;
      s += v0 + v1 + v2 + v3;
      s2 += v0 * v0 + v1 * v1 + v2 * v2 + v3 * v3;
    }
    ps[r][sg] = s; ps2[r][sg] = s2;
  }
  __syncthreads();
  if (tid < 64){
    float s  = ps[tid][0] + ps[tid][1] + ps[tid][2] + ps[tid][3];
    float s2 = ps2[tid][0] + ps2[tid][1] + ps2[tid][2] + ps2[tid][3];
    float mu = s * (1.f / 128.f);
    smu[tid] = mu;
    srs[tid] = rsqrtf(s2 * (1.f / 128.f) - mu * mu + 1e-5f);
  }
  __syncthreads();
  {
    float mu = smu[r], rs = srs[r];
#pragma unroll
    for (int i = 0; i < 32; i++){
      int col = sg * 32 + i;
      sA[r][col] = f2b((h[i] - mu) * rs * g[col] + bb[col]);
    }
  }
  __syncthreads();
  const int lane = tid & 63, wv = tid >> 6, l15 = lane & 15, q = lane >> 4;
  // GEMM1: (64x128) @ (128x256)
  floatx4 a1[16];
#pragma unroll
  for (int i = 0; i < 16; i++) a1[i] = (floatx4)(0.0f);
#pragma unroll
  for (int kk = 0; kk < 4; kk++){
    bf16x8 av = *(const bf16x8*)&sA[wv * 16 + l15][kk * 32 + q * 8];
#pragma unroll
    for (int nt = 0; nt < 16; nt++){
      bf16x8 bv = *(const bf16x8*)(lw1p + (size_t)((kk * 256 + nt * 16 + l15) * 4 + q) * 8);
      a1[nt] = __builtin_amdgcn_mfma_f32_16x16x32_bf16(av, bv, a1[nt], 0, 0, 0);
    }
  }
#pragma unroll
  for (int nt = 0; nt < 16; nt++){
    int col = nt * 16 + l15;
    float bval = lb1[col];
#pragma unroll
    for (int rr = 0; rr < 4; rr++)
      sY[wv * 16 + q * 4 + rr][col] = f2b(geluf(a1[nt][rr] + bval));
  }
  __syncthreads();
  // GEMM2: (64x256) @ (256x128)
  floatx4 a2[8];
#pragma unroll
  for (int i = 0; i < 8; i++) a2[i] = (floatx4)(0.0f);
#pragma unroll
  for (int kk = 0; kk < 8; kk++){
    bf16x8 av = *(const bf16x8*)&sY[wv * 16 + l15][kk * 32 + q * 8];
#pragma unroll
    for (int nt = 0; nt < 8; nt++){
      bf16x8 bv = *(const bf16x8*)(lw2p + (size_t)((kk * 128 + nt * 16 + l15) * 4 + q) * 8);
      a2[nt] = __builtin_amdgcn_mfma_f32_16x16x32_bf16(av, bv, a2[nt], 0, 0, 0);
    }
  }
#pragma unroll
  for (int nt = 0; nt < 8; nt++){
    int col = nt * 16 + l15;
    float bval = lb2[col];
#pragma unroll
    for (int rr = 0; rr < 4; rr++){
      int row = wv * 16 + q * 4 + rr;
      int gr = m0 + row;
      int tok = stok[row], c = gr & 7;
      float hres = emb[(size_t)tok * 128 + col] + pos[c * 128 + col];
      outL[(size_t)gr * 128 + col] = f2b(a2[nt][rr] + bval + hres);
    }
  }
}

// ---------------------------------------------------------------------------
// Generic MFMA GEMM: out = [gelu](A @ Bp + bias). 64 rows/block, 4 waves.
// ATYPE: 0 = bf16 rows (pitch a_pitch), 1 = mean over 8 consecutive bf16 rows
//        of pitch-128 source (chunk pooling). Output bf16 pitch o_pitch.
// ---------------------------------------------------------------------------
template<int K, int N, int ATYPE, bool GELU>
__global__ __launch_bounds__(256) void k_gemm(
    const u16* __restrict__ A, int a_pitch, const u16* __restrict__ Bp,
    const float* __restrict__ bias, u16* __restrict__ out, int o_pitch)
{
  __shared__ u16 sA[64][K + 8];
  const int tid = threadIdx.x;
  const int m0 = blockIdx.x * 64;
  const int r = tid >> 2, sg = tid & 3;
  constexpr int CPT = K / 4;
  if constexpr (ATYPE == 0){
    const uint4* src = (const uint4*)(A + (size_t)(m0 + r) * a_pitch + sg * CPT);
    uint4* dst = (uint4*)&sA[r][sg * CPT];
#pragma unroll
    for (int i = 0; i < CPT / 8; i++) dst[i] = src[i];
  } else {
    float accm[32];
#pragma unroll
    for (int i = 0; i < 32; i++) accm[i] = 0.f;
#pragma unroll
    for (int c = 0; c < 8; c++){
      const uint4* src = (const uint4*)(A + ((size_t)(m0 + r) * 8 + c) * 128 + sg * 32);
#pragma unroll
      for (int i = 0; i < 4; i++){
        uint4 v = src[i];
        unsigned wrd[4] = {v.x, v.y, v.z, v.w};
#pragma unroll
        for (int j = 0; j < 4; j++){
          accm[i * 8 + j * 2]     += lo2f(wrd[j]);
          accm[i * 8 + j * 2 + 1] += hi2f(wrd[j]);
        }
      }
    }
#pragma unroll
    for (int i = 0; i < 32; i++) sA[r][sg * 32 + i] = f2b(accm[i] * 0.125f);
  }
  __syncthreads();
  const int lane = tid & 63, wv = tid >> 6, l15 = lane & 15, q = lane >> 4;
  constexpr int NT = N / 16;
  floatx4 acc[NT];
#pragma unroll
  for (int i = 0; i < NT; i++) acc[i] = (floatx4)(0.0f);
#pragma unroll
  for (int kk = 0; kk < K / 32; kk++){
    bf16x8 av = *(const bf16x8*)&sA[wv * 16 + l15][kk * 32 + q * 8];
#pragma unroll
    for (int nt = 0; nt < NT; nt++){
      bf16x8 bv = *(const bf16x8*)(Bp + (size_t)((kk * N + nt * 16 + l15) * 4 + q) * 8);
      acc[nt] = __builtin_amdgcn_mfma_f32_16x16x32_bf16(av, bv, acc[nt], 0, 0, 0);
    }
  }
#pragma unroll
  for (int nt = 0; nt < NT; nt++){
    int col = nt * 16 + l15;
    float bval = bias ? bias[col] : 0.f;
#pragma unroll
    for (int rr = 0; rr < 4; rr++){
      int row = wv * 16 + q * 4 + rr;
      float v = acc[nt][rr] + bval;
      if (GELU) v = geluf(v);
      out[(size_t)(m0 + row) * o_pitch + col] = f2b(v);
    }
  }
}

// ---------------------------------------------------------------------------
// k_msg: s[n] = (1/count) * sum_{d=0..min(i,4)} gelu(P[n] + Q[n-d] + b1)
// PQ rows: [P | Q] bf16 pitch 256. One wave per node, 2 dims/lane.
// ---------------------------------------------------------------------------
__global__ __launch_bounds__(256) void k_msg(const u16* __restrict__ PQ,
                                             const float* __restrict__ b1,
                                             u16* __restrict__ sOut)
{
  int node = blockIdx.x * 4 + (threadIdx.x >> 6);
  int lane = threadIdx.x & 63;
  int i = node & 1023;
  int cnt = (i + 1 < 5) ? (i + 1) : 5;
  int d0 = lane * 2;
  unsigned pv = *(const unsigned*)(PQ + (size_t)node * 256 + d0);
  float p0 = lo2f(pv) + b1[d0], p1 = hi2f(pv) + b1[d0 + 1];
  float a0 = 0.f, a1 = 0.f;
  for (int d = 0; d < cnt; d++){
    unsigned qv = *(const unsigned*)(PQ + (size_t)(node - d) * 256 + 128 + d0);
    a0 += geluf(p0 + lo2f(qv));
    a1 += geluf(p1 + hi2f(qv));
  }
  float inv = 1.f / (float)cnt;
  unsigned pack = (unsigned)f2b(a0 * inv) | (((unsigned)f2b(a1 * inv)) << 16);
  *(unsigned*)(sOut + (size_t)node * 128 + d0) = pack;
}

// ---------------------------------------------------------------------------
// k_ln: hmsg = LN(hmsg + upd) * g + b, in place on cat[:,0:128] (bf16)
// ---------------------------------------------------------------------------
__global__ __launch_bounds__(256) void k_ln(u16* __restrict__ cat,
                                            const u16* __restrict__ upd,
                                            const float* __restrict__ g,
                                            const float* __restrict__ bb)
{
  int node = blockIdx.x * 4 + (threadIdx.x >> 6);
  int lane = threadIdx.x & 63;
  int d0 = lane * 2;
  unsigned hv = *(const unsigned*)(cat + (size_t)node * 256 + d0);
  unsigned uv = *(const unsigned*)(upd + (size_t)node * 128 + d0);
  float x0 = lo2f(hv) + lo2f(uv);
  float x1 = hi2f(hv) + hi2f(uv);
  float s = x0 + x1, s2 = x0 * x0 + x1 * x1;
#pragma unroll
  for (int off = 32; off; off >>= 1){
    s += __shfl_xor(s, off, 64);
    s2 += __shfl_xor(s2, off, 64);
  }
  float mu = s * (1.f / 128.f);
  float rs = rsqrtf(s2 * (1.f / 128.f) - mu * mu + 1e-5f);
  float y0 = (x0 - mu) * rs * g[d0] + bb[d0];
  float y1 = (x1 - mu) * rs * g[d0 + 1] + bb[d0 + 1];
  unsigned pack = (unsigned)f2b(y0) | (((unsigned)f2b(y1)) << 16);
  *(unsigned*)(cat + (size_t)node * 256 + d0) = pack;
}

// ---------------------------------------------------------------------------
// k_head: out = LN(local + bc[chunk]) @ head_w  (131072 x 128 x 256), f32 out
// ---------------------------------------------------------------------------
__global__ __launch_bounds__(256) void k_head(
    const u16* __restrict__ localL, const u16* __restrict__ bcB,
    const float* __restrict__ g, const float* __restrict__ bb,
    const u16* __restrict__ headp, float* __restrict__ out)
{
  __shared__ u16 sA[64][136];
  __shared__ float ps[64][4], ps2[64][4], smu[64], srs[64];
  const int tid = threadIdx.x;
  const int m0 = blockIdx.x * 64;
  const int r = tid >> 2, sg = tid & 3;
  float h[32];
  {
    const int gr = m0 + r;
    const int ch = gr >> 3;
    const uint4* l4 = (const uint4*)(localL + (size_t)gr * 128 + sg * 32);
    const uint4* c4 = (const uint4*)(bcB + (size_t)ch * 128 + sg * 32);
    float s = 0.f, s2 = 0.f;
#pragma unroll
    for (int i = 0; i < 4; i++){
      uint4 lv = l4[i], cv = c4[i];
      unsigned lw[4] = {lv.x, lv.y, lv.z, lv.w}, cw[4] = {cv.x, cv.y, cv.z, cv.w};
#pragma unroll
      for (int j = 0; j < 4; j++){
        float v0 = lo2f(lw[j]) + lo2f(cw[j]);
        float v1 = hi2f(lw[j]) + hi2f(cw[j]);
        h[i * 8 + j * 2] = v0; h[i * 8 + j * 2 + 1] = v1;
        s += v0 + v1; s2 += v0 * v0 + v1 * v1;
      }
    }
    ps[r][sg] = s; ps2[r][sg] = s2;
  }
  __syncthreads();
  if (tid < 64){
    float s  = ps[tid][0] + ps[tid][1] + ps[tid][2] + ps[tid][3];
    float s2 = ps2[tid][0] + ps2[tid][1] + ps2[tid][2] + ps2[tid][3];
    float mu = s * (1.f / 128.f);
    smu[tid] = mu;
    srs[tid] = rsqrtf(s2 * (1.f / 128.f) - mu * mu + 1e-5f);
  }
  __syncthreads();
  {
    float mu = smu[r], rs = srs[r];
#pragma unroll
    for (int i = 0; i < 32; i++){
      int col = sg * 32 + i;
      sA[r][col] = f2b((h[i] - mu) * rs * g[col] + bb[col]);
    }
  }
  __syncthreads();
  const int lane = tid & 63, wv = tid >> 6, l15 = lane & 15, q = lane >> 4;
  floatx4 acc[16];
#pragma unroll
  for (int i = 0; i < 16; i++) acc[i] = (floatx4)(0.0f);
#pragma unroll
  for (int kk = 0; kk < 4; kk++){
    bf16x8 av = *(const bf16x8*)&sA[wv * 16 + l15][kk * 32 + q * 8];
#pragma unroll
    for (int nt = 0; nt < 16; nt++){
      bf16x8 bv = *(const bf16x8*)(headp + (size_t)((kk * 256 + nt * 16 + l15) * 4 + q) * 8);
      acc[nt] = __builtin_amdgcn_mfma_f32_16x16x32_bf16(av, bv, acc[nt], 0, 0, 0);
    }
  }
#pragma unroll
  for (int nt = 0; nt < 16; nt++){
    int col = nt * 16 + l15;
#pragma unroll
    for (int rr = 0; rr < 4; rr++){
      int row = wv * 16 + q * 4 + rr;
      out[(size_t)(m0 + row) * 256 + col] = acc[nt][rr];
    }
  }
}

// ---------------------------------------------------------------------------

extern "C" void kernel_launch(void* const* d_in, const int* in_sizes, int n_in,
                              void* d_out, int out_size, void* d_ws, size_t ws_size,
                              hipStream_t stream)
{
  const int*   x     = (const int*)d_in[0];
  const float* emb   = (const float*)d_in[1];
  const float* pos   = (const float*)d_in[2];
  const float* lw1   = (const float*)d_in[3];
  const float* lb1   = (const float*)d_in[4];
  const float* lw2   = (const float*)d_in[5];
  const float* lb2   = (const float*)d_in[6];
  const float* llng  = (const float*)d_in[7];
  const float* llnb  = (const float*)d_in[8];
  const float* poolw = (const float*)d_in[9];
  const float* poolb = (const float*)d_in[10];
  const float* mw1   = (const float*)d_in[11];
  const float* mb1   = (const float*)d_in[12];
  const float* mw2   = (const float*)d_in[13];
  const float* mb2   = (const float*)d_in[14];
  const float* uw1   = (const float*)d_in[15];
  const float* ub1   = (const float*)d_in[16];
  const float* uw2   = (const float*)d_in[17];
  const float* ub2   = (const float*)d_in[18];
  const float* mlng  = (const float*)d_in[19];
  const float* mlnb  = (const float*)d_in[20];
  const float* bcw   = (const float*)d_in[21];
  const float* bcb   = (const float*)d_in[22];
  const float* flng  = (const float*)d_in[23];
  const float* flnb  = (const float*)d_in[24];
  const float* headw = (const float*)d_in[25];

  // ws layout (~38.3 MB): packed weights | localB bf16 | bcB bf16
  char* ws = (char*)d_ws;
  u16* wpack  = (u16*)ws;                  // 458,752 B used of 512 KB
  u16* lw1p  = wpack;
  u16* lw2p  = wpack + 32768;
  u16* poolp = wpack + 65536;
  u16* mw1p  = wpack + 81920;
  u16* mw2p  = wpack + 114688;
  u16* uw1p  = wpack + 131072;
  u16* uw2p  = wpack + 163840;
  u16* bcp   = wpack + 180224;
  u16* headp = wpack + 196608;
  u16* localB = (u16*)(ws + 524288);       // 131072 x 128 bf16 = 33.55 MB
  u16* bcB    = (u16*)(ws + 34078720);     // 16384 x 128 bf16  = 4.19 MB

  // transient node-level scratch lives in d_out (dead before k_head, which
  // overwrites all of d_out); offsets < 25.2 MB, safe for any out dtype
  char* ob = (char*)d_out;
  u16* catB = (u16*)(ob);                  // 16384 x 256 bf16 [hmsg | agg]
  u16* PQ   = (u16*)(ob + 8388608);        // 16384 x 256 bf16 [P | Q]
  u16* sB   = (u16*)(ob + 16777216);       // 16384 x 128 bf16
  u16* t2B  = PQ;                          // aliases PQ (dead after k_msg)
  u16* updB = (u16*)(ob + 20971520);       // 16384 x 128 bf16

  k_pack<<<896, 256, 0, stream>>>(lw1, lw2, poolw, mw1, mw2, uw1, uw2, bcw, headw, wpack);
  k_local<<<2048, 256, 0, stream>>>(x, emb, pos, lw1p, lb1, lw2p, lb2, llng, llnb, localB);
  // hmsg = mean8(local) @ pool_w + pool_b  -> catB[:,0:128]
  k_gemm<128, 128, 1, false><<<256, 256, 0, stream>>>(localB, 128, poolp, poolb, catB, 256);
  for (int rnd = 0; rnd < 3; rnd++){
    // [P|Q] = hmsg @ [w1_top | w1_bot]
    k_gemm<128, 256, 0, false><<<256, 256, 0, stream>>>(catB, 256, mw1p, nullptr, PQ, 256);
    k_msg<<<4096, 256, 0, stream>>>(PQ, mb1, sB);
    // agg = s @ msg_w2 + msg_b2 -> catB[:,128:256]
    k_gemm<128, 128, 0, false><<<256, 256, 0, stream>>>(sB, 128, mw2p, mb2, catB + 128, 256);
    // t2 = gelu(cat @ upd_w1 + upd_b1)
    k_gemm<256, 128, 0, true><<<256, 256, 0, stream>>>(catB, 256, uw1p, ub1, t2B, 128);
    // upd = t2 @ upd_w2 + upd_b2
    k_gemm<128, 128, 0, false><<<256, 256, 0, stream>>>(t2B, 128, uw2p, ub2, updB, 128);
    // hmsg = LN(hmsg + upd) in place
    k_ln<<<4096, 256, 0, stream>>>(catB, updB, mlng, mlnb);
  }
  // bc = hmsg @ bc_w + bc_b
  k_gemm<128, 128, 0, false><<<256, 256, 0, stream>>>(catB, 256, bcp, bcb, bcB, 128);
  k_head<<<2048, 256, 0, stream>>>(localB, bcB, flng, flnb, headp, (float*)d_out);
}

// Round 6
// 574.377 us; speedup vs baseline: 1.0030x; 1.0030x over previous
//
#include <hip/hip_runtime.h>

typedef unsigned short u16;
typedef __attribute__((ext_vector_type(8))) __bf16 bf16x8;
typedef __attribute__((ext_vector_type(4))) float floatx4;

#define DEV static __device__ __forceinline__

DEV float lo2f(unsigned v){ return __uint_as_float(v << 16); }
DEV float hi2f(unsigned v){ return __uint_as_float(v & 0xffff0000u); }
DEV float bu2f(u16 v){ return __uint_as_float(((unsigned)v) << 16); }
DEV u16 f2b(float f){
  unsigned u = __float_as_uint(f);
  return (u16)((u + 0x7fffu + ((u >> 16) & 1u)) >> 16);
}
// fast erf-gelu: Abramowitz-Stegun 7.1.26, |err_erf| < 1.5e-7
DEV float geluf(float x){
  float u  = x * 0.70710678118654752440f;
  float au = fabsf(u);
  float t  = 1.0f / fmaf(0.3275911f, au, 1.0f);
  float p  = t*(0.254829592f + t*(-0.284496736f + t*(1.421413741f +
             t*(-1.453152027f + t*1.061405429f))));
  float e  = __expf(-au*au);
  float E  = fmaf(-p, e, 1.0f);
  float er = copysignf(E, u);
  return 0.5f * x * (1.0f + er);
}

// ---------------------------------------------------------------------------
// Weight pre-pack: f32 B (K x N row-major) -> bf16 frag layout
//   dst[((kk*N + n)*4 + q)*8 + j] = B[kk*32 + q*8 + j][n]
// ---------------------------------------------------------------------------
__global__ __launch_bounds__(256) void k_pack(
    const float* __restrict__ lw1, const float* __restrict__ lw2, const float* __restrict__ poolw,
    const float* __restrict__ mw1, const float* __restrict__ mw2, const float* __restrict__ uw1,
    const float* __restrict__ uw2, const float* __restrict__ bcw, const float* __restrict__ headw,
    u16* __restrict__ dst)
{
  int b = blockIdx.x;
  const float* src; int N, off, remap = 0;
  if      (b < 128){            src = lw1;  N=256; off = 0;      }
  else if (b < 256){ b -= 128;  src = lw2;  N=128; off = 32768;  }
  else if (b < 320){ b -= 256;  src = poolw;N=128; off = 65536;  }
  else if (b < 448){ b -= 320;  src = mw1;  N=256; off = 81920;  remap = 1; }
  else if (b < 512){ b -= 448;  src = mw2;  N=128; off = 114688; }
  else if (b < 640){ b -= 512;  src = uw1;  N=128; off = 131072; }
  else if (b < 704){ b -= 640;  src = uw2;  N=128; off = 163840; }
  else if (b < 768){ b -= 704;  src = bcw;  N=128; off = 180224; }
  else             { b -= 768;  src = headw;N=256; off = 196608; }
  int e = b * 256 + threadIdx.x;
  int j = e & 7, q = (e >> 3) & 3, rest = e >> 5;
  int n = rest % N, kk = rest / N;
  int k = kk * 32 + q * 8 + j;
  float v;
  if (remap) v = (n < 128) ? src[k * 128 + n] : src[(128 + k) * 128 + (n - 128)];
  else       v = src[k * N + n];
  dst[off + e] = f2b(v);
}

// ---------------------------------------------------------------------------
// k_local (R2-proven structure): h = emb[tok]+pos[c];
// local = h + gelu(LN(h)@lw1+lb1)@lw2+lb2. 64 tokens/block, 4 waves.
// R6 changes vs R2: fast gelu; sY shrunk to [64][136] via half-split of
// GEMM1/GEMM2 (2 extra uniform barriers per half). LDS 54272 -> 37632 B.
// ---------------------------------------------------------------------------
__global__ __launch_bounds__(256) void k_local(
    const int* __restrict__ x, const float* __restrict__ emb, const float* __restrict__ pos,
    const u16* __restrict__ lw1p, const float* __restrict__ lb1,
    const u16* __restrict__ lw2p, const float* __restrict__ lb2,
    const float* __restrict__ g, const float* __restrict__ bb, u16* __restrict__ outL)
{
  __shared__ u16 sA[64][136];     // LN'd activations bf16
  __shared__ u16 sY[64][136];     // gelu hidden bf16 (one 128-col half at a time)
  __shared__ int stok[64];
  __shared__ float ps[64][4], ps2[64][4], smu[64], srs[64];
  const int tid = threadIdx.x;
  const int m0 = blockIdx.x * 64;
  if (tid < 64) stok[tid] = x[m0 + tid];
  __syncthreads();
  const int r = tid >> 2, sg = tid & 3;
  float h[32];
  {
    const int tok = stok[r];
    const int c = (m0 + r) & 7;
    const float4* e4 = (const float4*)(emb + (size_t)tok * 128 + sg * 32);
    const float4* p4 = (const float4*)(pos + c * 128 + sg * 32);
    float s = 0.f, s2 = 0.f;
#pragma unroll
    for (int i = 0; i < 8; i++){
      float4 ev = e4[i], pv = p4[i];
      float v0 = ev.x + pv.x, v1 = ev.y + pv.y, v2 = ev.z + pv.z, v3 = ev.w + pv.w;
      h[i * 4 + 0] = v0; h[i * 4 + 1] = v1; h[i * 4 + 2] = v2; h[i * 4 + 3] = v3;
      s += v0 + v1 + v2 + v3;
      s2 += v0 * v0 + v1 * v1 + v2 * v2 + v3 * v3;
    }
    ps[r][sg] = s; ps2[r][sg] = s2;
  }
  __syncthreads();
  if (tid < 64){
    float s  = ps[tid][0] + ps[tid][1] + ps[tid][2] + ps[tid][3];
    float s2 = ps2[tid][0] + ps2[tid][1] + ps2[tid][2] + ps2[tid][3];
    float mu = s * (1.f / 128.f);
    smu[tid] = mu;
    srs[tid] = rsqrtf(s2 * (1.f / 128.f) - mu * mu + 1e-5f);
  }
  __syncthreads();
  {
    float mu = smu[r], rs = srs[r];
#pragma unroll
    for (int i = 0; i < 32; i++){
      int col = sg * 32 + i;
      sA[r][col] = f2b((h[i] - mu) * rs * g[col] + bb[col]);
    }
  }
  __syncthreads();
  const int lane = tid & 63, wv = tid >> 6, l15 = lane & 15, q = lane >> 4;
  // GEMM1 (64x128)@(128x256) and GEMM2 (64x256)@(256x128), N1/K2 split in halves
  floatx4 a2[8];
#pragma unroll
  for (int i = 0; i < 8; i++) a2[i] = (floatx4)(0.0f);
#pragma unroll
  for (int half = 0; half < 2; half++){
    floatx4 a1[8];
#pragma unroll
    for (int i = 0; i < 8; i++) a1[i] = (floatx4)(0.0f);
#pragma unroll
    for (int kk = 0; kk < 4; kk++){
      bf16x8 av = *(const bf16x8*)&sA[wv * 16 + l15][kk * 32 + q * 8];
#pragma unroll
      for (int nt = 0; nt < 8; nt++){
        bf16x8 bv = *(const bf16x8*)(lw1p + (size_t)((kk * 256 + (half * 8 + nt) * 16 + l15) * 4 + q) * 8);
        a1[nt] = __builtin_amdgcn_mfma_f32_16x16x32_bf16(av, bv, a1[nt], 0, 0, 0);
      }
    }
    __syncthreads();   // previous half's sY reads complete before overwrite
#pragma unroll
    for (int nt = 0; nt < 8; nt++){
      int col = nt * 16 + l15;
      float bval = lb1[half * 128 + col];
#pragma unroll
      for (int rr = 0; rr < 4; rr++)
        sY[wv * 16 + q * 4 + rr][col] = f2b(geluf(a1[nt][rr] + bval));
    }
    __syncthreads();   // Y-half writes visible
#pragma unroll
    for (int k = 0; k < 4; k++){
      bf16x8 yv = *(const bf16x8*)&sY[wv * 16 + l15][k * 32 + q * 8];
#pragma unroll
      for (int nt = 0; nt < 8; nt++){
        bf16x8 bv = *(const bf16x8*)(lw2p + (size_t)(((half * 4 + k) * 128 + nt * 16 + l15) * 4 + q) * 8);
        a2[nt] = __builtin_amdgcn_mfma_f32_16x16x32_bf16(yv, bv, a2[nt], 0, 0, 0);
      }
    }
  }
#pragma unroll
  for (int nt = 0; nt < 8; nt++){
    int col = nt * 16 + l15;
    float bval = lb2[col];
#pragma unroll
    for (int rr = 0; rr < 4; rr++){
      int row = wv * 16 + q * 4 + rr;
      int gr = m0 + row;
      int tok = stok[row], c = gr & 7;
      float hres = emb[(size_t)tok * 128 + col] + pos[c * 128 + col];
      outL[(size_t)gr * 128 + col] = f2b(a2[nt][rr] + bval + hres);
    }
  }
}

// ---------------------------------------------------------------------------
// Generic MFMA GEMM: out = [gelu](A @ Bp + bias). 64 rows/block, 4 waves.
// ATYPE: 0 = bf16 rows (pitch a_pitch), 1 = mean over 8 consecutive bf16 rows
//        of pitch-128 source (chunk pooling). Output bf16 pitch o_pitch.
// ---------------------------------------------------------------------------
template<int K, int N, int ATYPE, bool GELU>
__global__ __launch_bounds__(256) void k_gemm(
    const u16* __restrict__ A, int a_pitch, const u16* __restrict__ Bp,
    const float* __restrict__ bias, u16* __restrict__ out, int o_pitch)
{
  __shared__ u16 sA[64][K + 8];
  const int tid = threadIdx.x;
  const int m0 = blockIdx.x * 64;
  const int r = tid >> 2, sg = tid & 3;
  constexpr int CPT = K / 4;
  if constexpr (ATYPE == 0){
    const uint4* src = (const uint4*)(A + (size_t)(m0 + r) * a_pitch + sg * CPT);
    uint4* dst = (uint4*)&sA[r][sg * CPT];
#pragma unroll
    for (int i = 0; i < CPT / 8; i++) dst[i] = src[i];
  } else {
    float accm[32];
#pragma unroll
    for (int i = 0; i < 32; i++) accm[i] = 0.f;
#pragma unroll
    for (int c = 0; c < 8; c++){
      const uint4* src = (const uint4*)(A + ((size_t)(m0 + r) * 8 + c) * 128 + sg * 32);
#pragma unroll
      for (int i = 0; i < 4; i++){
        uint4 v = src[i];
        unsigned wrd[4] = {v.x, v.y, v.z, v.w};
#pragma unroll
        for (int j = 0; j < 4; j++){
          accm[i * 8 + j * 2]     += lo2f(wrd[j]);
          accm[i * 8 + j * 2 + 1] += hi2f(wrd[j]);
        }
      }
    }
#pragma unroll
    for (int i = 0; i < 32; i++) sA[r][sg * 32 + i] = f2b(accm[i] * 0.125f);
  }
  __syncthreads();
  const int lane = tid & 63, wv = tid >> 6, l15 = lane & 15, q = lane >> 4;
  constexpr int NT = N / 16;
  floatx4 acc[NT];
#pragma unroll
  for (int i = 0; i < NT; i++) acc[i] = (floatx4)(0.0f);
#pragma unroll
  for (int kk = 0; kk < K / 32; kk++){
    bf16x8 av = *(const bf16x8*)&sA[wv * 16 + l15][kk * 32 + q * 8];
#pragma unroll
    for (int nt = 0; nt < NT; nt++){
      bf16x8 bv = *(const bf16x8*)(Bp + (size_t)((kk * N + nt * 16 + l15) * 4 + q) * 8);
      acc[nt] = __builtin_amdgcn_mfma_f32_16x16x32_bf16(av, bv, acc[nt], 0, 0, 0);
    }
  }
#pragma unroll
  for (int nt = 0; nt < NT; nt++){
    int col = nt * 16 + l15;
    float bval = bias ? bias[col] : 0.f;
#pragma unroll
    for (int rr = 0; rr < 4; rr++){
      int row = wv * 16 + q * 4 + rr;
      float v = acc[nt][rr] + bval;
      if (GELU) v = geluf(v);
      out[(size_t)(m0 + row) * o_pitch + col] = f2b(v);
    }
  }
}

// ---------------------------------------------------------------------------
// k_msg: s[n] = (1/count) * sum_{d=0..min(i,4)} gelu(P[n] + Q[n-d] + b1)
// PQ rows: [P | Q] bf16 pitch 256. One wave per node, 2 dims/lane.
// ---------------------------------------------------------------------------
__global__ __launch_bounds__(256) void k_msg(const u16* __restrict__ PQ,
                                             const float* __restrict__ b1,
                                             u16* __restrict__ sOut)
{
  int node = blockIdx.x * 4 + (threadIdx.x >> 6);
  int lane = threadIdx.x & 63;
  int i = node & 1023;
  int cnt = (i + 1 < 5) ? (i + 1) : 5;
  int d0 = lane * 2;
  unsigned pv = *(const unsigned*)(PQ + (size_t)node * 256 + d0);
  float p0 = lo2f(pv) + b1[d0], p1 = hi2f(pv) + b1[d0 + 1];
  float a0 = 0.f, a1 = 0.f;
  for (int d = 0; d < cnt; d++){
    unsigned qv = *(const unsigned*)(PQ + (size_t)(node - d) * 256 + 128 + d0);
    a0 += geluf(p0 + lo2f(qv));
    a1 += geluf(p1 + hi2f(qv));
  }
  float inv = 1.f / (float)cnt;
  unsigned pack = (unsigned)f2b(a0 * inv) | (((unsigned)f2b(a1 * inv)) << 16);
  *(unsigned*)(sOut + (size_t)node * 128 + d0) = pack;
}

// ---------------------------------------------------------------------------
// k_ln: hmsg = LN(hmsg + upd) * g + b, in place on cat[:,0:128] (bf16)
// ---------------------------------------------------------------------------
__global__ __launch_bounds__(256) void k_ln(u16* __restrict__ cat,
                                            const u16* __restrict__ upd,
                                            const float* __restrict__ g,
                                            const float* __restrict__ bb)
{
  int node = blockIdx.x * 4 + (threadIdx.x >> 6);
  int lane = threadIdx.x & 63;
  int d0 = lane * 2;
  unsigned hv = *(const unsigned*)(cat + (size_t)node * 256 + d0);
  unsigned uv = *(const unsigned*)(upd + (size_t)node * 128 + d0);
  float x0 = lo2f(hv) + lo2f(uv);
  float x1 = hi2f(hv) + hi2f(uv);
  float s = x0 + x1, s2 = x0 * x0 + x1 * x1;
#pragma unroll
  for (int off = 32; off; off >>= 1){
    s += __shfl_xor(s, off, 64);
    s2 += __shfl_xor(s2, off, 64);
  }
  float mu = s * (1.f / 128.f);
  float rs = rsqrtf(s2 * (1.f / 128.f) - mu * mu + 1e-5f);
  float y0 = (x0 - mu) * rs * g[d0] + bb[d0];
  float y1 = (x1 - mu) * rs * g[d0 + 1] + bb[d0 + 1];
  unsigned pack = (unsigned)f2b(y0) | (((unsigned)f2b(y1)) << 16);
  *(unsigned*)(cat + (size_t)node * 256 + d0) = pack;
}

// ---------------------------------------------------------------------------
// k_head: out = LN(local + bc[chunk]) @ head_w  (131072 x 128 x 256), f32 out
// ---------------------------------------------------------------------------
__global__ __launch_bounds__(256) void k_head(
    const u16* __restrict__ localL, const u16* __restrict__ bcB,
    const float* __restrict__ g, const float* __restrict__ bb,
    const u16* __restrict__ headp, float* __restrict__ out)
{
  __shared__ u16 sA[64][136];
  __shared__ float ps[64][4], ps2[64][4], smu[64], srs[64];
  const int tid = threadIdx.x;
  const int m0 = blockIdx.x * 64;
  const int r = tid >> 2, sg = tid & 3;
  float h[32];
  {
    const int gr = m0 + r;
    const int ch = gr >> 3;
    const uint4* l4 = (const uint4*)(localL + (size_t)gr * 128 + sg * 32);
    const uint4* c4 = (const uint4*)(bcB + (size_t)ch * 128 + sg * 32);
    float s = 0.f, s2 = 0.f;
#pragma unroll
    for (int i = 0; i < 4; i++){
      uint4 lv = l4[i], cv = c4[i];
      unsigned lw[4] = {lv.x, lv.y, lv.z, lv.w}, cw[4] = {cv.x, cv.y, cv.z, cv.w};
#pragma unroll
      for (int j = 0; j < 4; j++){
        float v0 = lo2f(lw[j]) + lo2f(cw[j]);
        float v1 = hi2f(lw[j]) + hi2f(cw[j]);
        h[i * 8 + j * 2] = v0; h[i * 8 + j * 2 + 1] = v1;
        s += v0 + v1; s2 += v0 * v0 + v1 * v1;
      }
    }
    ps[r][sg] = s; ps2[r][sg] = s2;
  }
  __syncthreads();
  if (tid < 64){
    float s  = ps[tid][0] + ps[tid][1] + ps[tid][2] + ps[tid][3];
    float s2 = ps2[tid][0] + ps2[tid][1] + ps2[tid][2] + ps2[tid][3];
    float mu = s * (1.f / 128.f);
    smu[tid] = mu;
    srs[tid] = rsqrtf(s2 * (1.f / 128.f) - mu * mu + 1e-5f);
  }
  __syncthreads();
  {
    float mu = smu[r], rs = srs[r];
#pragma unroll
    for (int i = 0; i < 32; i++){
      int col = sg * 32 + i;
      sA[r][col] = f2b((h[i] - mu) * rs * g[col] + bb[col]);
    }
  }
  __syncthreads();
  const int lane = tid & 63, wv = tid >> 6, l15 = lane & 15, q = lane >> 4;
  floatx4 acc[16];
#pragma unroll
  for (int i = 0; i < 16; i++) acc[i] = (floatx4)(0.0f);
#pragma unroll
  for (int kk = 0; kk < 4; kk++){
    bf16x8 av = *(const bf16x8*)&sA[wv * 16 + l15][kk * 32 + q * 8];
#pragma unroll
    for (int nt = 0; nt < 16; nt++){
      bf16x8 bv = *(const bf16x8*)(headp + (size_t)((kk * 256 + nt * 16 + l15) * 4 + q) * 8);
      acc[nt] = __builtin_amdgcn_mfma_f32_16x16x32_bf16(av, bv, acc[nt], 0, 0, 0);
    }
  }
#pragma unroll
  for (int nt = 0; nt < 16; nt++){
    int col = nt * 16 + l15;
#pragma unroll
    for (int rr = 0; rr < 4; rr++){
      int row = wv * 16 + q * 4 + rr;
      out[(size_t)(m0 + row) * 256 + col] = acc[nt][rr];
    }
  }
}

// ---------------------------------------------------------------------------

extern "C" void kernel_launch(void* const* d_in, const int* in_sizes, int n_in,
                              void* d_out, int out_size, void* d_ws, size_t ws_size,
                              hipStream_t stream)
{
  const int*   x     = (const int*)d_in[0];
  const float* emb   = (const float*)d_in[1];
  const float* pos   = (const float*)d_in[2];
  const float* lw1   = (const float*)d_in[3];
  const float* lb1   = (const float*)d_in[4];
  const float* lw2   = (const float*)d_in[5];
  const float* lb2   = (const float*)d_in[6];
  const float* llng  = (const float*)d_in[7];
  const float* llnb  = (const float*)d_in[8];
  const float* poolw = (const float*)d_in[9];
  const float* poolb = (const float*)d_in[10];
  const float* mw1   = (const float*)d_in[11];
  const float* mb1   = (const float*)d_in[12];
  const float* mw2   = (const float*)d_in[13];
  const float* mb2   = (const float*)d_in[14];
  const float* uw1   = (const float*)d_in[15];
  const float* ub1   = (const float*)d_in[16];
  const float* uw2   = (const float*)d_in[17];
  const float* ub2   = (const float*)d_in[18];
  const float* mlng  = (const float*)d_in[19];
  const float* mlnb  = (const float*)d_in[20];
  const float* bcw   = (const float*)d_in[21];
  const float* bcb   = (const float*)d_in[22];
  const float* flng  = (const float*)d_in[23];
  const float* flnb  = (const float*)d_in[24];
  const float* headw = (const float*)d_in[25];

  // ws layout (~38.3 MB): packed weights | localB bf16 | bcB bf16
  char* ws = (char*)d_ws;
  u16* wpack = (u16*)ws;
  u16* lw1p  = wpack;
  u16* lw2p  = wpack + 32768;
  u16* poolp = wpack + 65536;
  u16* mw1p  = wpack + 81920;
  u16* mw2p  = wpack + 114688;
  u16* uw1p  = wpack + 131072;
  u16* uw2p  = wpack + 163840;
  u16* bcp   = wpack + 180224;
  u16* headp = wpack + 196608;
  u16* localB = (u16*)(ws + 524288);       // 131072 x 128 bf16 = 33.55 MB
  u16* bcB    = (u16*)(ws + 34078720);     // 16384 x 128 bf16  = 4.19 MB

  // transient node-level scratch lives in d_out (dead before k_head, which
  // overwrites all of d_out); offsets < 25.2 MB
  char* ob = (char*)d_out;
  u16* catB = (u16*)(ob);                  // 16384 x 256 bf16 [hmsg | agg]
  u16* PQ   = (u16*)(ob + 8388608);        // 16384 x 256 bf16 [P | Q]
  u16* sB   = (u16*)(ob + 16777216);       // 16384 x 128 bf16
  u16* t2B  = PQ;                          // aliases PQ (dead after k_msg)
  u16* updB = (u16*)(ob + 20971520);       // 16384 x 128 bf16

  k_pack<<<896, 256, 0, stream>>>(lw1, lw2, poolw, mw1, mw2, uw1, uw2, bcw, headw, wpack);
  k_local<<<2048, 256, 0, stream>>>(x, emb, pos, lw1p, lb1, lw2p, lb2, llng, llnb, localB);
  // hmsg = mean8(local) @ pool_w + pool_b  -> catB[:,0:128]
  k_gemm<128, 128, 1, false><<<256, 256, 0, stream>>>(localB, 128, poolp, poolb, catB, 256);
  for (int rnd = 0; rnd < 3; rnd++){
    // [P|Q] = hmsg @ [w1_top | w1_bot]
    k_gemm<128, 256, 0, false><<<256, 256, 0, stream>>>(catB, 256, mw1p, nullptr, PQ, 256);
    k_msg<<<4096, 256, 0, stream>>>(PQ, mb1, sB);
    // agg = s @ msg_w2 + msg_b2 -> catB[:,128:256]
    k_gemm<128, 128, 0, false><<<256, 256, 0, stream>>>(sB, 128, mw2p, mb2, catB + 128, 256);
    // t2 = gelu(cat @ upd_w1 + upd_b1)
    k_gemm<256, 128, 0, true><<<256, 256, 0, stream>>>(catB, 256, uw1p, ub1, t2B, 128);
    // upd = t2 @ upd_w2 + upd_b2
    k_gemm<128, 128, 0, false><<<256, 256, 0, stream>>>(t2B, 128, uw2p, ub2, updB, 128);
    // hmsg = LN(hmsg + upd) in place
    k_ln<<<4096, 256, 0, stream>>>(catB, updB, mlng, mlnb);
  }
  // bc = hmsg @ bc_w + bc_b
  k_gemm<128, 128, 0, false><<<256, 256, 0, stream>>>(catB, 256, bcp, bcb, bcB, 128);
  k_head<<<2048, 256, 0, stream>>>(localB, bcB, flng, flnb, headp, (float*)d_out);
}